// Round 5
// baseline (1949.509 us; speedup 1.0000x reference)
//
#include <hip/hip_runtime.h>
#include <hip/hip_fp16.h>

#define TENC 64
#define TDEC 18
#define NDEC 24
#define NF1  17
#define NF2  129
#define HH   128

// ---- ws layout ----
// fp32 region (float indices)
#define OFF_WX   0        // [32][128] float4  (Wx packed [kk][j])
#define OFF_WI   16384    // [16][64] float4
#define OFF_WI2  20480    // [16][64] float4
// u32 region (uint indices into ws viewed as uint*)
#define U_GB     24576    // [37][1024] f16-pair gate weights, phase B
#define U_GD     62464    // [65][1024] phase D
#define U_GF     129024   // [64][1024] phase F
#define U_WE     194560   // [64][128]  We  (pr = i*8+pq)
#define U_WE2    202752   // [64][128]  We2
#define U_WH     210944   // [128][128] Wh  (pr = i*4+pq)

#define SB   68     // WiX/Wi2X row stride (floats)
#define SWF  132    // WxF row stride
#define XIN  1200   // xin region offset inside big[bb]
#define BIGN 8772

typedef _Float16 h2t __attribute__((ext_vector_type(2)));

#if defined(__has_builtin)
#if __has_builtin(__builtin_amdgcn_fdot2)
#define HAVE_FDOT2 1
#endif
#endif

// compile-time-constant loop: guarantees constant indices at template
// instantiation time, BEFORE SROA -> arrays stay in registers (rule #20).
template<int I> struct ic_t { static constexpr int v = I; };
template<int N, typename F>
__device__ __forceinline__ void sfor(F&& f)
{
    if constexpr (N > 0) { sfor<N - 1>((F&&)f); f(ic_t<N - 1>{}); }
}

__device__ __forceinline__ float fdot2p(unsigned w, unsigned x, float acc)
{
    h2t hw = __builtin_bit_cast(h2t, w);
    h2t hx = __builtin_bit_cast(h2t, x);
#ifdef HAVE_FDOT2
    return __builtin_amdgcn_fdot2(hw, hx, acc, false);
#else
    return acc + (float)hw.x * (float)hx.x + (float)hw.y * (float)hx.y;
#endif
}

__device__ __forceinline__ unsigned pkh_d(float a, float b)
{
    __half ha = __float2half(a), hb = __float2half(b);
    return (unsigned)__half_as_ushort(ha) | ((unsigned)__half_as_ushort(hb) << 16);
}

__device__ __forceinline__ float fsig(float x) { return 1.f / (1.f + __expf(-x)); }
__device__ __forceinline__ float ftanh(float x)
{
    x = fminf(fmaxf(x, -15.f), 15.f);
    float e = __expf(2.f * x);
    return (e - 1.f) / (e + 1.f);
}
__device__ __forceinline__ float dot4(float4 a, float4 b)
{ return a.x * b.x + a.y * b.y + a.z * b.z + a.w * b.w; }

// ---------------- pack kernels ----------------
__global__ void pack_f3(const float* Wx, const float* Wi, const float* Wi2, float* ws)
{
    const int m = blockIdx.y;
    const float* src; int G, K, off;
    if (m == 0)      { src = Wx;  G = 128; K = 128; off = OFF_WX; }
    else if (m == 1) { src = Wi;  G = 64;  K = 64;  off = OFF_WI; }
    else             { src = Wi2; G = 64;  K = 64;  off = OFF_WI2; }
    const int n = G * K;
    for (int i = blockIdx.x * blockDim.x + threadIdx.x; i < n; i += gridDim.x * blockDim.x) {
        int q = i & 3, gk = i >> 2;
        int kk = gk / G, g = gk - kk * G;
        ws[off + i] = src[g * K + kk * 4 + q];
    }
}

// gate weights: column for tid = [Wih row (padded to KXP) | Whh row]; pair q = p*NP + i
__global__ void pack_gate(const float* Wih, const float* Whh, int Kx, int KXP, int TP, int NP,
                          unsigned base, unsigned* wsu)
{
    const int i = blockIdx.x;
    const int tid = threadIdx.x;
    const int p = tid >> 9, g = tid & 511;
    const int q = p * NP + i;
    unsigned v = 0;
    if (q < TP) {
        int k0 = 2 * q, k1 = 2 * q + 1;
        float f0 = (k0 < KXP) ? ((k0 < Kx) ? Wih[g * Kx + k0] : 0.f) : Whh[g * HH + (k0 - KXP)];
        float f1 = (k1 < KXP) ? ((k1 < Kx) ? Wih[g * Kx + k1] : 0.f) : Whh[g * HH + (k1 - KXP)];
        v = pkh_d(f0, f1);
    }
    wsu[base + (unsigned)i * 1024u + tid] = v;
}

// e-weights: dst[j*128 + pq*nI + i] = pair (i*nPQ + pq) of row j (K=256 -> 128 pairs)
__global__ void pack_ew(const float* W, int J, int nPQ, int nI, unsigned base, unsigned* wsu)
{
    int idx = blockIdx.x * blockDim.x + threadIdx.x;
    if (idx >= J * 128) return;
    int j = idx >> 7, r = idx & 127;
    int pq = r / nI, i = r - pq * nI;
    int pr = i * nPQ + pq;
    wsu[base + idx] = pkh_d(W[j * 256 + 2 * pr], W[j * 256 + 2 * pr + 1]);
}

// ---------------- main kernel ----------------
// 1024 threads = 16 waves = 4 waves/EU at 1 WG/CU (LDS forces 1 WG/CU anyway).
// waves_per_eu(4,4) pins the VGPR budget at 128/wave so the persistent
// weight arrays (promoted via sfor's constant indices) fit in registers.
__global__ __launch_bounds__(1024)
__attribute__((amdgpu_waves_per_eu(4, 4)))
void dstp_main(const float* __restrict__ inq, const float* __restrict__ labp,
               const float* __restrict__ bih1, const float* __restrict__ bhh1,
               const float* __restrict__ bih2, const float* __restrict__ bhh2,
               const float* __restrict__ bihd, const float* __restrict__ bhhd,
               const float* __restrict__ Wi_b, const float* __restrict__ Vd_w, const float* __restrict__ Vd_b,
               const float* __restrict__ Wi2_b, const float* __restrict__ Vd2_w, const float* __restrict__ Vd2_b,
               const float* __restrict__ Wx_b, const float* __restrict__ V_w, const float* __restrict__ V_b,
               const float* __restrict__ reg_w, const float* __restrict__ reg_b,
               const float* __restrict__ ws, float* __restrict__ out)
{
    __shared__ __align__(16) float buf[2][TENC][HH];   // mid then final (fp32)
    __shared__ __align__(16) float big[2][BIGN];       // WiX+xin / Wi2X / WxF
    __shared__ unsigned hcp[2][128];                   // f16 pairs: [h 0..63 | c 64..127]
    __shared__ unsigned xhp[2][130];                   // f16 pairs: [x-part | h-part]
    __shared__ __align__(16) float ebuf[2][128];
    __shared__ float sc[2][NF2];
    __shared__ float att[2][64];
    __shared__ float pre2[2][2][512];                  // [khalf][bb][gate]
    __shared__ float lab[2][TENC];
    __shared__ __align__(16) float vw1[64], vw2[64], vwf[128], rw[128];
    __shared__ float rsm[4];

    const int tid  = threadIdx.x;
    const int lane = tid & 63;
    const int b0   = blockIdx.x * 2;
    const int p    = tid >> 9;     // k-half (wave-uniform)
    const int g    = tid & 511;    // gate index
    const int r9   = tid & 511;
    const unsigned* wsu = (const unsigned*)ws;
    const float4* Wxp = (const float4*)(ws + OFF_WX);
    const float4* Wip = (const float4*)(ws + OFF_WI);
    const float4* Wi2p = (const float4*)(ws + OFF_WI2);

    const float bg1 = p ? 0.f : (bih1[g] + bhh1[g]);
    const float bg2 = p ? 0.f : (bih2[g] + bhh2[g]);
    const float bgd = p ? 0.f : (bihd[g] + bhhd[g]);
    float creg = 0.f;   // fp32 cell state, lives in pointwise thread (tid<256)

    // ================= Phase A: inputs, WiX =================
    if (tid < 128) lab[tid >> 6][tid & 63] = labp[(b0 + (tid >> 6)) * TENC + (tid & 63)];
    if (tid < 64)        vw1[tid]       = Vd_w[tid];
    else if (tid < 128)  vw2[tid - 64]  = Vd2_w[tid - 64];
    else if (tid < 256)  vwf[tid - 128] = V_w[tid - 128];
    else if (tid < 384)  rw[tid - 256]  = reg_w[tid - 256];
    for (int i = tid; i < 2176; i += 1024) {            // xin: x[t][f], COLS skip 14
        int bb = i / 1088, r = i - bb * 1088, t = r / NF1, f = r - t * NF1;
        big[bb][XIN + r] = inq[((b0 + bb) * TENC + t) * 18 + f + (f >= 14)];
    }
    __syncthreads();
    for (int i = tid; i < 2176; i += 1024) {            // WiX[f][j]
        int bb = i / 1088, r = i - bb * 1088, f = r >> 6, j = r & 63;
        float acc = Wi_b[j];
        for (int tt = 0; tt < 16; ++tt) {
            float4 w = Wip[tt * 64 + j];
            acc += big[bb][XIN + (4 * tt + 0) * NF1 + f] * w.x
                 + big[bb][XIN + (4 * tt + 1) * NF1 + f] * w.y
                 + big[bb][XIN + (4 * tt + 2) * NF1 + f] * w.z
                 + big[bb][XIN + (4 * tt + 3) * NF1 + f] * w.w;
        }
        big[bb][f * SB + j] = acc;
    }

    // ================= Phase B: encoder scan 1 =================
    {
        if (tid < 130) { xhp[0][tid] = 0u; xhp[1][tid] = 0u; }
        if (tid < 128) { hcp[0][tid] = 0u; hcp[1][tid] = 0u; }
        creg = 0.f;
        unsigned wB[37];
        sfor<37>([&](auto I) { wB[I.v] = wsu[U_GB + I.v * 1024 + tid]; });
        unsigned we[16];
        {
            const int eb = U_WE + ((r9 >> 3) << 7) + ((r9 & 7) << 4);
            sfor<16>([&](auto I) { we[I.v] = wsu[eb + I.v]; });
        }
        __syncthreads();

        for (int t = 0; t < TENC; ++t) {
            {   // e[j] = [h,c] @ We.T  (f16 dot2, conflict-free pr = i*8+pq)
                int bb = tid >> 9, j = r9 >> 3, pq = r9 & 7;
                float acc = 0.f;
                sfor<16>([&](auto I) { acc = fdot2p(we[I.v], hcp[bb][I.v * 8 + pq], acc); });
                acc += __shfl_xor(acc, 1, 8);
                acc += __shfl_xor(acc, 2, 8);
                acc += __shfl_xor(acc, 4, 8);
                if (pq == 0) ebuf[bb][j] = acc;
            }
            __syncthreads();
            if (tid < 544) {   // score[f]: 16 threads per (bb,f)
                int bb = tid / 272, r = tid - bb * 272, f = r >> 4, pp = r & 15;
                float4 wx = *(const float4*)&big[bb][f * SB + pp * 4];
                float4 e4 = *(const float4*)&ebuf[bb][pp * 4];
                float4 v4 = *(const float4*)&vw1[pp * 4];
                float acc = ftanh(wx.x + e4.x) * v4.x + ftanh(wx.y + e4.y) * v4.y
                          + ftanh(wx.z + e4.z) * v4.z + ftanh(wx.w + e4.w) * v4.w;
                acc += __shfl_xor(acc, 1, 16);
                acc += __shfl_xor(acc, 2, 16);
                acc += __shfl_xor(acc, 4, 16);
                acc += __shfl_xor(acc, 8, 16);
                if (pp == 0) sc[bb][f] = acc + Vd_b[0];
            }
            __syncthreads();
            if (tid < 128) {   // softmax(17) + pack xav pairs
                int bb = tid >> 6, l = tid & 63;
                float v = (l < NF1) ? sc[bb][l] : -1e30f;
                float m = v;
                for (int d = 32; d; d >>= 1) m = fmaxf(m, __shfl_xor(m, d, 64));
                float e = (l < NF1) ? __expf(v - m) : 0.f;
                float s = e;
                for (int d = 32; d; d >>= 1) s += __shfl_xor(s, d, 64);
                float xv = (l < NF1) ? big[bb][XIN + t * NF1 + l] * (e / s) : 0.f;
                float xp = __shfl_xor(xv, 1, 64);
                if (!(l & 1) && l < 18) xhp[bb][l >> 1] = pkh_d(xv, xp);
            }
            __syncthreads();
            {   // gates from persisted regs; x via readlane broadcast
                unsigned xA0 = xhp[0][p * 37 + lane];
                unsigned xA1 = xhp[1][p * 37 + lane];
                float a0 = bg1, a1 = bg1;
                sfor<37>([&](auto I) {
                    unsigned s0 = __builtin_amdgcn_readlane(xA0, I.v);
                    unsigned s1 = __builtin_amdgcn_readlane(xA1, I.v);
                    a0 = fdot2p(wB[I.v], s0, a0);
                    a1 = fdot2p(wB[I.v], s1, a1);
                });
                pre2[p][0][g] = a0; pre2[p][1][g] = a1;
            }
            __syncthreads();
            if (tid < 256) {   // LSTM pointwise (c in register)
                int bb = tid >> 7, k = tid & 127;
                float gi = pre2[0][bb][k]       + pre2[1][bb][k];
                float gf = pre2[0][bb][128 + k] + pre2[1][bb][128 + k];
                float gg = pre2[0][bb][256 + k] + pre2[1][bb][256 + k];
                float go = pre2[0][bb][384 + k] + pre2[1][bb][384 + k];
                float c2 = fsig(gf) * creg + fsig(gi) * ftanh(gg);
                float h2v = fsig(go) * ftanh(c2);
                creg = c2;
                buf[bb][t][k] = h2v;
                float hp = __shfl_xor(h2v, 1, 64);
                float cp = __shfl_xor(c2, 1, 64);
                if (!(k & 1)) {
                    unsigned hu = pkh_d(h2v, hp);
                    hcp[bb][k >> 1] = hu;
                    hcp[bb][64 + (k >> 1)] = pkh_d(c2, cp);
                    xhp[bb][9 + (k >> 1)] = hu;
                }
            }
            __syncthreads();
        }
    }

    // ================= Phase C: Wi2X =================
    for (int i = tid; i < 16512; i += 1024) {
        int bb = i / 8256, r = i - bb * 8256, f = r >> 6, j = r & 63;
        float acc = Wi2_b[j];
        for (int tt = 0; tt < 16; ++tt) {
            float4 w = Wi2p[tt * 64 + j];
            float m0, m1, m2, m3;
            if (f < HH) {
                m0 = buf[bb][4 * tt][f];     m1 = buf[bb][4 * tt + 1][f];
                m2 = buf[bb][4 * tt + 2][f]; m3 = buf[bb][4 * tt + 3][f];
            } else {
                m0 = lab[bb][4 * tt];     m1 = lab[bb][4 * tt + 1];
                m2 = lab[bb][4 * tt + 2]; m3 = lab[bb][4 * tt + 3];
            }
            acc += m0 * w.x + m1 * w.y + m2 * w.z + m3 * w.w;
        }
        big[bb][f * SB + j] = acc;
    }

    // ================= Phase D: encoder scan 2 =================
    {
        if (tid < 130) { xhp[0][tid] = 0u; xhp[1][tid] = 0u; }
        if (tid < 128) { hcp[0][tid] = 0u; hcp[1][tid] = 0u; }
        creg = 0.f;
        unsigned wD[65];
        sfor<65>([&](auto I) { wD[I.v] = wsu[U_GD + I.v * 1024 + tid]; });
        unsigned we[16];
        {
            const int eb = U_WE2 + ((r9 >> 3) << 7) + ((r9 & 7) << 4);
            sfor<16>([&](auto I) { we[I.v] = wsu[eb + I.v]; });
        }
        __syncthreads();

        for (int t = 0; t < TENC; ++t) {
            {   // e[j] = [h,c] @ We2.T
                int bb = tid >> 9, j = r9 >> 3, pq = r9 & 7;
                float acc = 0.f;
                sfor<16>([&](auto I) { acc = fdot2p(we[I.v], hcp[bb][I.v * 8 + pq], acc); });
                acc += __shfl_xor(acc, 1, 8);
                acc += __shfl_xor(acc, 2, 8);
                acc += __shfl_xor(acc, 4, 8);
                if (pq == 0) ebuf[bb][j] = acc;
            }
            __syncthreads();
            for (int i = tid; i < 1032; i += 1024) {   // score[f]: 4 threads per (bb,f)
                int bb = i / 516, r = i - bb * 516, f = r >> 2, pp = i & 3;
                float acc = 0.f;
                #pragma unroll
                for (int c = 0; c < 4; ++c) {
                    float4 wx = *(const float4*)&big[bb][f * SB + pp * 16 + c * 4];
                    float4 e4 = *(const float4*)&ebuf[bb][pp * 16 + c * 4];
                    float4 v4 = *(const float4*)&vw2[pp * 16 + c * 4];
                    acc += ftanh(wx.x + e4.x) * v4.x + ftanh(wx.y + e4.y) * v4.y
                         + ftanh(wx.z + e4.z) * v4.z + ftanh(wx.w + e4.w) * v4.w;
                }
                acc += __shfl_xor(acc, 1, 4);
                acc += __shfl_xor(acc, 2, 4);
                if (pp == 0) sc[bb][f] = acc + Vd2_b[0];
            }
            __syncthreads();
            if (tid < 128) {   // softmax(129) + pack xav pairs
                int bb = tid >> 6, l = tid & 63;
                float s1 = sc[bb][l], s2 = sc[bb][l + 64];
                float s3 = (l == 0) ? sc[bb][128] : -1e30f;
                float m = fmaxf(fmaxf(s1, s2), s3);
                for (int d = 32; d; d >>= 1) m = fmaxf(m, __shfl_xor(m, d, 64));
                float e1 = __expf(s1 - m), e2 = __expf(s2 - m);
                float e3 = (l == 0) ? __expf(s3 - m) : 0.f;
                float s = e1 + e2 + e3;
                for (int d = 32; d; d >>= 1) s += __shfl_xor(s, d, 64);
                float inv = 1.f / s;
                float v1 = buf[bb][t][l] * e1 * inv;
                float v2 = buf[bb][t][l + 64] * e2 * inv;
                float v1p = __shfl_xor(v1, 1, 64);
                float v2p = __shfl_xor(v2, 1, 64);
                if (!(l & 1)) {
                    xhp[bb][l >> 1] = pkh_d(v1, v1p);
                    xhp[bb][32 + (l >> 1)] = pkh_d(v2, v2p);
                }
                if (l == 0) xhp[bb][64] = pkh_d(lab[bb][t] * e3 * inv, 0.f);
            }
            __syncthreads();
            {   // gates
                unsigned xA0 = xhp[0][p * 65 + lane];
                unsigned xA1 = xhp[1][p * 65 + lane];
                float a0 = bg2, a1 = bg2;
                sfor<64>([&](auto I) {
                    unsigned s0 = __builtin_amdgcn_readlane(xA0, I.v);
                    unsigned s1 = __builtin_amdgcn_readlane(xA1, I.v);
                    a0 = fdot2p(wD[I.v], s0, a0);
                    a1 = fdot2p(wD[I.v], s1, a1);
                });
                {   // pair index BASE+64 (uniform broadcast read; zero-padded for p=1)
                    unsigned u0 = xhp[0][p * 65 + 64];
                    unsigned u1 = xhp[1][p * 65 + 64];
                    a0 = fdot2p(wD[64], u0, a0);
                    a1 = fdot2p(wD[64], u1, a1);
                }
                pre2[p][0][g] = a0; pre2[p][1][g] = a1;
            }
            __syncthreads();
            if (tid < 256) {
                int bb = tid >> 7, k = tid & 127;
                float gi = pre2[0][bb][k]       + pre2[1][bb][k];
                float gf = pre2[0][bb][128 + k] + pre2[1][bb][128 + k];
                float gg = pre2[0][bb][256 + k] + pre2[1][bb][256 + k];
                float go = pre2[0][bb][384 + k] + pre2[1][bb][384 + k];
                float c2 = fsig(gf) * creg + fsig(gi) * ftanh(gg);
                float h2v = fsig(go) * ftanh(c2);
                creg = c2;
                buf[bb][t][k] = h2v;            // final overwrites consumed mid row
                float hp = __shfl_xor(h2v, 1, 64);
                float cp = __shfl_xor(c2, 1, 64);
                if (!(k & 1)) {
                    unsigned hu = pkh_d(h2v, hp);
                    hcp[bb][k >> 1] = hu;
                    hcp[bb][64 + (k >> 1)] = pkh_d(c2, cp);
                    xhp[bb][65 + (k >> 1)] = hu;
                }
            }
            __syncthreads();
        }
    }

    // ================= Phase E: WxF =================
    for (int i = tid; i < 16384; i += 1024) {
        int bb = i >> 13, r = i & 8191, tt = r >> 7, j = r & 127;
        float acc = Wx_b[j];
        const float4* bv = (const float4*)buf[bb][tt];
        #pragma unroll 8
        for (int kk = 0; kk < 32; ++kk)
            acc += dot4(Wxp[kk * 128 + j], bv[kk]);
        big[bb][tt * SWF + j] = acc;
    }

    // ================= Phase F: decoder =================
    {
        if (tid < 130) { xhp[0][tid] = 0u; xhp[1][tid] = 0u; }
        if (tid < 128) { hcp[0][tid] = 0u; hcp[1][tid] = 0u; }
        creg = 0.f;
        unsigned wF[64];
        sfor<64>([&](auto I) { wF[I.v] = wsu[U_GF + I.v * 1024 + tid]; });
        unsigned wh[32];
        {
            const int hb = U_WH + ((r9 >> 2) << 7) + ((r9 & 3) << 5);
            sfor<32>([&](auto I) { wh[I.v] = wsu[hb + I.v]; });
        }
        __syncthreads();

        for (int n = 0; n < NDEC; ++n) {
            {   // e[j] = [h,c] @ Wh.T  (j<128, pq<4, pr = i*4+pq)
                int bb = tid >> 9, j = r9 >> 2, pq = r9 & 3;
                float acc = 0.f;
                sfor<32>([&](auto I) { acc = fdot2p(wh[I.v], hcp[bb][I.v * 4 + pq], acc); });
                acc += __shfl_xor(acc, 1, 4);
                acc += __shfl_xor(acc, 2, 4);
                if (pq == 0) ebuf[bb][j] = acc;
            }
            __syncthreads();
            {   // s[tt]: 8 threads per (bb,tt)
                int bb = tid >> 9, tt = r9 >> 3, pp = r9 & 7;
                float acc = 0.f;
                #pragma unroll
                for (int c = 0; c < 4; ++c) {
                    float4 wx = *(const float4*)&big[bb][tt * SWF + pp * 16 + c * 4];
                    float4 e4 = *(const float4*)&ebuf[bb][pp * 16 + c * 4];
                    float4 v4 = *(const float4*)&vwf[pp * 16 + c * 4];
                    acc += ftanh(wx.x + e4.x) * v4.x + ftanh(wx.y + e4.y) * v4.y
                         + ftanh(wx.z + e4.z) * v4.z + ftanh(wx.w + e4.w) * v4.w;
                }
                acc += __shfl_xor(acc, 1, 8);
                acc += __shfl_xor(acc, 2, 8);
                acc += __shfl_xor(acc, 4, 8);
                if (pp == 0) sc[bb][tt] = acc + V_b[0];
            }
            __syncthreads();
            if (tid < 128) {   // softmax(64) over time
                int bb = tid >> 6, l = tid & 63;
                float v = sc[bb][l];
                float m = v;
                for (int d = 32; d; d >>= 1) m = fmaxf(m, __shfl_xor(m, d, 64));
                float e = __expf(v - m);
                float s = e;
                for (int d = 32; d; d >>= 1) s += __shfl_xor(s, d, 64);
                att[bb][l] = e / s;
            }
            __syncthreads();
            {   // din[k] = sum_t a[t]*final[t][k]; pack pairs
                int bb = tid >> 9, k = r9 >> 2, pq = r9 & 3;
                float acc = 0.f;
                #pragma unroll
                for (int u = 0; u < 16; ++u) {
                    int tt = u * 4 + pq;
                    acc += att[bb][tt] * buf[bb][tt][k];
                }
                acc += __shfl_xor(acc, 1, 64);
                acc += __shfl_xor(acc, 2, 64);   // all 4 pq lanes now hold din_k
                float dp = __shfl_xor(acc, 4, 64);   // partner k^1
                if (pq == 0 && !(k & 1)) xhp[bb][k >> 1] = pkh_d(acc, dp);
            }
            __syncthreads();
            {   // gates
                unsigned xA0 = xhp[0][p * 64 + lane];
                unsigned xA1 = xhp[1][p * 64 + lane];
                float a0 = bgd, a1 = bgd;
                sfor<64>([&](auto I) {
                    unsigned s0 = __builtin_amdgcn_readlane(xA0, I.v);
                    unsigned s1 = __builtin_amdgcn_readlane(xA1, I.v);
                    a0 = fdot2p(wF[I.v], s0, a0);
                    a1 = fdot2p(wF[I.v], s1, a1);
                });
                pre2[p][0][g] = a0; pre2[p][1][g] = a1;
            }
            __syncthreads();
            if (tid < 256) {   // pointwise + fused output partial
                int bb = tid >> 7, k = tid & 127;
                float gi = pre2[0][bb][k]       + pre2[1][bb][k];
                float gf = pre2[0][bb][128 + k] + pre2[1][bb][128 + k];
                float gg = pre2[0][bb][256 + k] + pre2[1][bb][256 + k];
                float go = pre2[0][bb][384 + k] + pre2[1][bb][384 + k];
                float c2 = fsig(gf) * creg + fsig(gi) * ftanh(gg);
                float h2v = fsig(go) * ftanh(c2);
                creg = c2;
                float hp = __shfl_xor(h2v, 1, 64);
                float cp = __shfl_xor(c2, 1, 64);
                if (!(k & 1)) {
                    unsigned hu = pkh_d(h2v, hp);
                    hcp[bb][k >> 1] = hu;
                    hcp[bb][64 + (k >> 1)] = pkh_d(c2, cp);
                    xhp[bb][64 + (k >> 1)] = hu;
                }
                if (n >= 6) {
                    float v = h2v * rw[k];
                    for (int d = 32; d; d >>= 1) v += __shfl_xor(v, d, 64);
                    if ((tid & 63) == 0) rsm[tid >> 6] = v;
                }
            }
            __syncthreads();
            if (n >= 6 && tid < 2)
                out[(b0 + tid) * TDEC + (n - 6)] = rsm[tid * 2] + rsm[tid * 2 + 1] + reg_b[0];
        }
    }
}

extern "C" void kernel_launch(void* const* d_in, const int* in_sizes, int n_in,
                              void* d_out, int out_size, void* d_ws, size_t ws_size,
                              hipStream_t stream)
{
    const float* inq   = (const float*)d_in[0];
    const float* labp  = (const float*)d_in[1];
    const float* Wih1  = (const float*)d_in[2];
    const float* Whh1  = (const float*)d_in[3];
    const float* bih1  = (const float*)d_in[4];
    const float* bhh1  = (const float*)d_in[5];
    const float* Wih2  = (const float*)d_in[6];
    const float* Whh2  = (const float*)d_in[7];
    const float* bih2  = (const float*)d_in[8];
    const float* bhh2  = (const float*)d_in[9];
    const float* Wihd  = (const float*)d_in[10];
    const float* Whhd  = (const float*)d_in[11];
    const float* bihd  = (const float*)d_in[12];
    const float* bhhd  = (const float*)d_in[13];
    const float* Wi_w  = (const float*)d_in[14];
    const float* Wi_b  = (const float*)d_in[15];
    const float* We_w  = (const float*)d_in[16];
    const float* Vd_w  = (const float*)d_in[17];
    const float* Vd_b  = (const float*)d_in[18];
    const float* Wi2_w = (const float*)d_in[19];
    const float* Wi2_b = (const float*)d_in[20];
    const float* We2_w = (const float*)d_in[21];
    const float* Vd2_w = (const float*)d_in[22];
    const float* Vd2_b = (const float*)d_in[23];
    const float* Wx_w  = (const float*)d_in[24];
    const float* Wx_b  = (const float*)d_in[25];
    const float* Wh_w  = (const float*)d_in[26];
    const float* V_w   = (const float*)d_in[27];
    const float* V_b   = (const float*)d_in[28];
    const float* reg_w = (const float*)d_in[29];
    const float* reg_b = (const float*)d_in[30];
    float* ws  = (float*)d_ws;
    unsigned* wsu = (unsigned*)d_ws;
    float* out = (float*)d_out;

    pack_f3<<<dim3(16, 3), 256, 0, stream>>>(Wx_w, Wi_w, Wi2_w, ws);
    pack_gate<<<37, 1024, 0, stream>>>(Wih1, Whh1, 17, 18, 73, 37, U_GB, wsu);
    pack_gate<<<65, 1024, 0, stream>>>(Wih2, Whh2, 129, 130, 129, 65, U_GD, wsu);
    pack_gate<<<64, 1024, 0, stream>>>(Wihd, Whhd, 128, 128, 128, 64, U_GF, wsu);
    pack_ew<<<8, 1024, 0, stream>>>(We_w, 64, 8, 16, U_WE, wsu);
    pack_ew<<<8, 1024, 0, stream>>>(We2_w, 64, 8, 16, U_WE2, wsu);
    pack_ew<<<16, 1024, 0, stream>>>(Wh_w, 128, 4, 32, U_WH, wsu);
    dstp_main<<<256, 1024, 0, stream>>>(inq, labp, bih1, bhh1, bih2, bhh2, bihd, bhhd,
                                        Wi_b, Vd_w, Vd_b, Wi2_b, Vd2_w, Vd2_b,
                                        Wx_b, V_w, V_b, reg_w, reg_b, ws, out);
}

// Round 6
// 1477.505 us; speedup vs baseline: 1.3195x; 1.3195x over previous
//
#include <hip/hip_runtime.h>
#include <hip/hip_fp16.h>

#define TENC 64
#define TDEC 18
#define NDEC 24
#define NF1  17
#define NF2  129
#define HH   128

// ---- ws layout ----
// fp32 region (float indices)
#define OFF_WX   0        // [32][128] float4
#define OFF_WI   16384    // [16][64] float4
#define OFF_WI2  20480    // [16][64] float4
// u32 region (uint indices)
#define U_GB   24576     // [73][512]  phase B gate pairs (x 0..8 | h 9..72)
#define U_GDH  61952     // [64][512]  phase D h-part (pairs 65..128)
#define U_GDX  94720     // [65][512]  phase D x-part (pairs 0..64) - streamed
#define U_GFH  128000    // [64][512]  phase F h-part (pairs 64..127)
#define U_GFX  160768    // [64][512]  phase F din-part (pairs 0..63) - streamed
#define U_WE   193536    // [64][128]  We   (pr = i*8+pq)
#define U_WE2  201728    // [64][128]  We2  - streamed per step
#define U_WH   209920    // [128][128] Wh   (pr = i*4+pq) - streamed per step

#define SB   68
#define SWF  132
#define XIN  1200
#define BIGN 8772

typedef _Float16 h2t __attribute__((ext_vector_type(2)));

#if defined(__has_builtin)
#if __has_builtin(__builtin_amdgcn_fdot2)
#define HAVE_FDOT2 1
#endif
#endif

template<int I> struct ic_t { static constexpr int v = I; };
template<int N, typename F>
__device__ __forceinline__ void sfor(F&& f)
{
    if constexpr (N > 0) { sfor<N - 1>((F&&)f); f(ic_t<N - 1>{}); }
}

__device__ __forceinline__ float fdot2p(unsigned w, unsigned x, float acc)
{
    h2t hw = __builtin_bit_cast(h2t, w);
    h2t hx = __builtin_bit_cast(h2t, x);
#ifdef HAVE_FDOT2
    return __builtin_amdgcn_fdot2(hw, hx, acc, false);
#else
    return acc + (float)hw.x * (float)hx.x + (float)hw.y * (float)hx.y;
#endif
}

__device__ __forceinline__ unsigned pkh_d(float a, float b)
{
    __half ha = __float2half(a), hb = __float2half(b);
    return (unsigned)__half_as_ushort(ha) | ((unsigned)__half_as_ushort(hb) << 16);
}

__device__ __forceinline__ float fsig(float x) { return 1.f / (1.f + __expf(-x)); }
__device__ __forceinline__ float ftanh(float x)
{
    x = fminf(fmaxf(x, -15.f), 15.f);
    float e = __expf(2.f * x);
    return (e - 1.f) / (e + 1.f);
}
__device__ __forceinline__ float dot4(float4 a, float4 b)
{ return a.x * b.x + a.y * b.y + a.z * b.z + a.w * b.w; }

// ---------------- pack kernels ----------------
__global__ void pack_f3(const float* Wx, const float* Wi, const float* Wi2, float* ws)
{
    const int m = blockIdx.y;
    const float* src; int G, K, off;
    if (m == 0)      { src = Wx;  G = 128; K = 128; off = OFF_WX; }
    else if (m == 1) { src = Wi;  G = 64;  K = 64;  off = OFF_WI; }
    else             { src = Wi2; G = 64;  K = 64;  off = OFF_WI2; }
    const int n = G * K;
    for (int i = blockIdx.x * blockDim.x + threadIdx.x; i < n; i += gridDim.x * blockDim.x) {
        int q = i & 3, gk = i >> 2;
        int kk = gk / G, g = gk - kk * G;
        ws[off + i] = src[g * K + kk * 4 + q];
    }
}

// pair (qbase+blockIdx.x) of column g = [Wih row g padded to KXP | Whh row g]
__global__ void pack_gp(const float* Wih, const float* Whh, int Kx, int KXP, int qbase,
                        unsigned base, unsigned* wsu)
{
    const int g = threadIdx.x;
    const int q = qbase + blockIdx.x;
    int k0 = 2 * q, k1 = 2 * q + 1;
    float f0 = (k0 < KXP) ? ((k0 < Kx) ? Wih[g * Kx + k0] : 0.f) : Whh[g * HH + (k0 - KXP)];
    float f1 = (k1 < KXP) ? ((k1 < Kx) ? Wih[g * Kx + k1] : 0.f) : Whh[g * HH + (k1 - KXP)];
    wsu[base + (unsigned)blockIdx.x * 512u + g] = pkh_d(f0, f1);
}

// e-weights: dst[j*128 + pq*nI + i] = pair (i*nPQ + pq) of row j
__global__ void pack_ew(const float* W, int J, int nPQ, int nI, unsigned base, unsigned* wsu)
{
    int idx = blockIdx.x * blockDim.x + threadIdx.x;
    if (idx >= J * 128) return;
    int j = idx >> 7, r = idx & 127;
    int pq = r / nI, i = r - pq * nI;
    int pr = i * nPQ + pq;
    wsu[base + idx] = pkh_d(W[j * 256 + 2 * pr], W[j * 256 + 2 * pr + 1]);
}

// ---------------- main kernel: 512 threads, 1 batch elem/WG, grid 512 ----------------
__global__ __launch_bounds__(512, 2)
void dstp_main(const float* __restrict__ inq, const float* __restrict__ labp,
               const float* __restrict__ bih1, const float* __restrict__ bhh1,
               const float* __restrict__ bih2, const float* __restrict__ bhh2,
               const float* __restrict__ bihd, const float* __restrict__ bhhd,
               const float* __restrict__ Wi_b, const float* __restrict__ Vd_w, const float* __restrict__ Vd_b,
               const float* __restrict__ Wi2_b, const float* __restrict__ Vd2_w, const float* __restrict__ Vd2_b,
               const float* __restrict__ Wx_b, const float* __restrict__ V_w, const float* __restrict__ V_b,
               const float* __restrict__ reg_w, const float* __restrict__ reg_b,
               const float* __restrict__ ws, float* __restrict__ out)
{
    __shared__ __align__(16) float buf[TENC][HH];     // mid then final
    __shared__ __align__(16) float big[BIGN];         // WiX+xin / Wi2X / WxF
    __shared__ unsigned hcp[128];                     // f16 pairs: h 0..63 | c 64..127
    __shared__ unsigned xhp[132];                     // broadcast pairs
    __shared__ __align__(16) float ebuf[128];
    __shared__ float sc[132];
    __shared__ float att[64];
    __shared__ float pre[512];
    __shared__ float lab[64];
    __shared__ __align__(16) float vw1[64], vw2[64], vwf[128], rw[128];
    __shared__ float rsm[2];

    const int tid  = threadIdx.x;
    const int lane = tid & 63;
    const int b    = blockIdx.x;
    const unsigned* wsu = (const unsigned*)ws;
    const float4* Wxp  = (const float4*)(ws + OFF_WX);
    const float4* Wip  = (const float4*)(ws + OFF_WI);
    const float4* Wi2p = (const float4*)(ws + OFF_WI2);

    const float bg1 = bih1[tid] + bhh1[tid];
    const float bg2 = bih2[tid] + bhh2[tid];
    const float bgd = bihd[tid] + bhhd[tid];
    float creg = 0.f;   // fp32 cell state (pointwise thread tid<128)

    // ================= Phase A: inputs, WiX =================
    if (tid < 64)        lab[tid]       = labp[b * TENC + tid];
    if (tid < 64)        vw1[tid]       = Vd_w[tid];
    else if (tid < 128)  vw2[tid - 64]  = Vd2_w[tid - 64];
    else if (tid < 256)  vwf[tid - 128] = V_w[tid - 128];
    else if (tid < 384)  rw[tid - 256]  = reg_w[tid - 256];
    for (int i = tid; i < 1088; i += 512) {           // xin: x[t][f], COLS skip 14
        int t = i / NF1, f = i - t * NF1;
        big[XIN + i] = inq[(b * TENC + t) * 18 + f + (f >= 14)];
    }
    __syncthreads();
    for (int i = tid; i < 1088; i += 512) {           // WiX[f][j]
        int f = i >> 6, j = i & 63;
        float acc = Wi_b[j];
        for (int tt = 0; tt < 16; ++tt) {
            float4 w = Wip[tt * 64 + j];
            acc += big[XIN + (4 * tt + 0) * NF1 + f] * w.x
                 + big[XIN + (4 * tt + 1) * NF1 + f] * w.y
                 + big[XIN + (4 * tt + 2) * NF1 + f] * w.z
                 + big[XIN + (4 * tt + 3) * NF1 + f] * w.w;
        }
        big[f * SB + j] = acc;
    }

    // ================= Phase B: encoder scan 1 (fully resident) =================
    {
        if (tid < 128) hcp[tid] = 0u;
        if (tid < 132) xhp[tid] = 0u;
        creg = 0.f;
        unsigned wB[73];
        sfor<73>([&](auto I) { wB[I.v] = wsu[U_GB + I.v * 512 + tid]; });
        unsigned we[16];
        const int ewb = U_WE + ((tid >> 3) << 7) + ((tid & 7) << 4);
        sfor<16>([&](auto I) { we[I.v] = wsu[ewb + I.v]; });
        __syncthreads();

        for (int t = 0; t < TENC; ++t) {
            {   // e[j] = [h,c] @ We.T
                int j = tid >> 3, pq = tid & 7;
                float acc = 0.f;
                sfor<16>([&](auto I) { acc = fdot2p(we[I.v], hcp[I.v * 8 + pq], acc); });
                acc += __shfl_xor(acc, 1, 8);
                acc += __shfl_xor(acc, 2, 8);
                acc += __shfl_xor(acc, 4, 8);
                if (pq == 0) ebuf[j] = acc;
            }
            __syncthreads();
            if (tid < 272) {   // score[f]: 16 threads per f
                int f = tid >> 4, pp = tid & 15;
                float4 wx = *(const float4*)&big[f * SB + pp * 4];
                float4 e4 = *(const float4*)&ebuf[pp * 4];
                float4 v4 = *(const float4*)&vw1[pp * 4];
                float acc = ftanh(wx.x + e4.x) * v4.x + ftanh(wx.y + e4.y) * v4.y
                          + ftanh(wx.z + e4.z) * v4.z + ftanh(wx.w + e4.w) * v4.w;
                acc += __shfl_xor(acc, 1, 16);
                acc += __shfl_xor(acc, 2, 16);
                acc += __shfl_xor(acc, 4, 16);
                acc += __shfl_xor(acc, 8, 16);
                if (pp == 0) sc[f] = acc + Vd_b[0];
            }
            __syncthreads();
            if (tid < 64) {   // softmax(17) + pack x pairs 0..8
                float v = (tid < NF1) ? sc[tid] : -1e30f;
                float m = v;
                for (int d = 32; d; d >>= 1) m = fmaxf(m, __shfl_xor(m, d, 64));
                float e = (tid < NF1) ? __expf(v - m) : 0.f;
                float s = e;
                for (int d = 32; d; d >>= 1) s += __shfl_xor(s, d, 64);
                float xv = (tid < NF1) ? big[XIN + t * NF1 + tid] * (e / s) : 0.f;
                float xp = __shfl_xor(xv, 1, 64);
                if (!(tid & 1) && tid < 18) xhp[tid >> 1] = pkh_d(xv, xp);
            }
            __syncthreads();
            {   // gates: x pairs 0..8, h pairs 9..72
                unsigned xA = xhp[lane], xB2 = xhp[64 + lane];
                float a = bg1;
                sfor<64>([&](auto I) { a = fdot2p(wB[I.v], __builtin_amdgcn_readlane(xA, I.v), a); });
                sfor<9>([&](auto I)  { a = fdot2p(wB[64 + I.v], __builtin_amdgcn_readlane(xB2, I.v), a); });
                pre[tid] = a;
            }
            __syncthreads();
            if (tid < 128) {   // LSTM pointwise
                int k = tid;
                float gi = pre[k], gf = pre[128 + k], gg = pre[256 + k], go = pre[384 + k];
                float c2 = fsig(gf) * creg + fsig(gi) * ftanh(gg);
                float h2v = fsig(go) * ftanh(c2);
                creg = c2;
                buf[t][k] = h2v;
                float hp = __shfl_xor(h2v, 1, 64);
                float cp = __shfl_xor(c2, 1, 64);
                if (!(k & 1)) {
                    unsigned hu = pkh_d(h2v, hp);
                    hcp[k >> 1] = hu;
                    hcp[64 + (k >> 1)] = pkh_d(c2, cp);
                    xhp[9 + (k >> 1)] = hu;
                }
            }
            __syncthreads();
        }
    }

    // ================= Phase C: Wi2X =================
    if (tid < 128) hcp[tid] = 0u;
    if (tid < 132) xhp[tid] = 0u;
    creg = 0.f;
    for (int i = tid; i < 8256; i += 512) {
        int f = i >> 6, j = i & 63;
        float acc = Wi2_b[j];
        for (int tt = 0; tt < 16; ++tt) {
            float4 w = Wi2p[tt * 64 + j];
            float m0, m1, m2, m3;
            if (f < HH) {
                m0 = buf[4 * tt][f];     m1 = buf[4 * tt + 1][f];
                m2 = buf[4 * tt + 2][f]; m3 = buf[4 * tt + 3][f];
            } else {
                m0 = lab[4 * tt];     m1 = lab[4 * tt + 1];
                m2 = lab[4 * tt + 2]; m3 = lab[4 * tt + 3];
            }
            acc += m0 * w.x + m1 * w.y + m2 * w.z + m3 * w.w;
        }
        big[f * SB + j] = acc;
    }

    // ================= Phase D: encoder scan 2 (h resident, x+We2 streamed) =================
    {
        unsigned wDh[64];
        sfor<64>([&](auto I) { wDh[I.v] = wsu[U_GDH + I.v * 512 + tid]; });
        __syncthreads();
        const int ewb2 = U_WE2 + ((tid >> 3) << 7) + ((tid & 7) << 4);

        for (int t = 0; t < TENC; ++t) {
            unsigned wes[16];
            sfor<16>([&](auto I) { wes[I.v] = wsu[ewb2 + I.v]; });
            unsigned c0[22];
            sfor<22>([&](auto I) { c0[I.v] = wsu[U_GDX + I.v * 512 + tid]; });
            {   // e[j] = [h,c] @ We2.T
                int j = tid >> 3, pq = tid & 7;
                float acc = 0.f;
                sfor<16>([&](auto I) { acc = fdot2p(wes[I.v], hcp[I.v * 8 + pq], acc); });
                acc += __shfl_xor(acc, 1, 8);
                acc += __shfl_xor(acc, 2, 8);
                acc += __shfl_xor(acc, 4, 8);
                if (pq == 0) ebuf[j] = acc;
            }
            __syncthreads();
            for (int i = tid; i < 516; i += 512) {   // score[f]: 4 threads per f
                int f = i >> 2, pp = i & 3;
                float acc = 0.f;
                #pragma unroll
                for (int c = 0; c < 4; ++c) {
                    float4 wx = *(const float4*)&big[f * SB + pp * 16 + c * 4];
                    float4 e4 = *(const float4*)&ebuf[pp * 16 + c * 4];
                    float4 v4 = *(const float4*)&vw2[pp * 16 + c * 4];
                    acc += ftanh(wx.x + e4.x) * v4.x + ftanh(wx.y + e4.y) * v4.y
                         + ftanh(wx.z + e4.z) * v4.z + ftanh(wx.w + e4.w) * v4.w;
                }
                acc += __shfl_xor(acc, 1, 4);
                acc += __shfl_xor(acc, 2, 4);
                if (pp == 0) sc[f] = acc + Vd2_b[0];
            }
            __syncthreads();
            if (tid < 64) {   // softmax(129) + pack x pairs 0..64
                float s1 = sc[tid], s2 = sc[tid + 64];
                float s3 = (tid == 0) ? sc[128] : -1e30f;
                float m = fmaxf(fmaxf(s1, s2), s3);
                for (int d = 32; d; d >>= 1) m = fmaxf(m, __shfl_xor(m, d, 64));
                float e1 = __expf(s1 - m), e2 = __expf(s2 - m);
                float e3 = (tid == 0) ? __expf(s3 - m) : 0.f;
                float s = e1 + e2 + e3;
                for (int d = 32; d; d >>= 1) s += __shfl_xor(s, d, 64);
                float inv = 1.f / s;
                float v1 = buf[t][tid] * e1 * inv;
                float v2 = buf[t][tid + 64] * e2 * inv;
                float v1p = __shfl_xor(v1, 1, 64);
                float v2p = __shfl_xor(v2, 1, 64);
                if (!(tid & 1)) {
                    xhp[tid >> 1] = pkh_d(v1, v1p);
                    xhp[32 + (tid >> 1)] = pkh_d(v2, v2p);
                }
                if (tid == 0) xhp[64] = pkh_d(lab[t] * e3 * inv, 0.f);
            }
            __syncthreads();
            {   // gates: streamed x chunks + resident h
                unsigned xA = xhp[lane], xB2 = xhp[64 + lane];
                unsigned u128 = xhp[128];
                float a = bg2;
                sfor<22>([&](auto I) { a = fdot2p(c0[I.v], __builtin_amdgcn_readlane(xA, I.v), a); });
                asm volatile("" ::: "memory");
                unsigned c1[22];
                sfor<22>([&](auto I) { c1[I.v] = wsu[U_GDX + (22 + I.v) * 512 + tid]; });
                sfor<22>([&](auto I) { a = fdot2p(c1[I.v], __builtin_amdgcn_readlane(xA, 22 + I.v), a); });
                asm volatile("" ::: "memory");
                unsigned c2a[21];
                sfor<21>([&](auto I) { c2a[I.v] = wsu[U_GDX + (44 + I.v) * 512 + tid]; });
                sfor<20>([&](auto I) { a = fdot2p(c2a[I.v], __builtin_amdgcn_readlane(xA, 44 + I.v), a); });
                a = fdot2p(c2a[20], __builtin_amdgcn_readlane(xB2, 0), a);   // pair 64
                sfor<63>([&](auto I) { a = fdot2p(wDh[I.v], __builtin_amdgcn_readlane(xB2, 1 + I.v), a); });
                a = fdot2p(wDh[63], u128, a);                                // pair 128
                pre[tid] = a;
            }
            __syncthreads();
            if (tid < 128) {
                int k = tid;
                float gi = pre[k], gf = pre[128 + k], gg = pre[256 + k], go = pre[384 + k];
                float c2 = fsig(gf) * creg + fsig(gi) * ftanh(gg);
                float h2v = fsig(go) * ftanh(c2);
                creg = c2;
                buf[t][k] = h2v;                    // final overwrites consumed mid row
                float hp = __shfl_xor(h2v, 1, 64);
                float cp = __shfl_xor(c2, 1, 64);
                if (!(k & 1)) {
                    unsigned hu = pkh_d(h2v, hp);
                    hcp[k >> 1] = hu;
                    hcp[64 + (k >> 1)] = pkh_d(c2, cp);
                    xhp[65 + (k >> 1)] = hu;
                }
            }
            __syncthreads();
        }
    }

    // ================= Phase E: WxF =================
    if (tid < 128) hcp[tid] = 0u;
    if (tid < 132) xhp[tid] = 0u;
    creg = 0.f;
    for (int i = tid; i < 8192; i += 512) {
        int tt = i >> 7, j = i & 127;
        float acc = Wx_b[j];
        const float4* bv = (const float4*)buf[tt];
        #pragma unroll 8
        for (int kk = 0; kk < 32; ++kk)
            acc += dot4(Wxp[kk * 128 + j], bv[kk]);
        big[tt * SWF + j] = acc;
    }

    // ================= Phase F: decoder (h resident, din+Wh streamed) =================
    {
        unsigned wFh[64];
        sfor<64>([&](auto I) { wFh[I.v] = wsu[U_GFH + I.v * 512 + tid]; });
        __syncthreads();
        const int whb = U_WH + ((tid >> 2) << 7) + ((tid & 3) << 5);

        for (int n = 0; n < NDEC; ++n) {
            {   // e[j] = [h,c] @ Wh.T (streamed wh, consumed immediately)
                unsigned whs[32];
                sfor<32>([&](auto I) { whs[I.v] = wsu[whb + I.v]; });
                int j = tid >> 2, pq = tid & 3;
                float acc = 0.f;
                sfor<32>([&](auto I) { acc = fdot2p(whs[I.v], hcp[I.v * 4 + pq], acc); });
                acc += __shfl_xor(acc, 1, 4);
                acc += __shfl_xor(acc, 2, 4);
                if (pq == 0) ebuf[j] = acc;
            }
            __syncthreads();
            unsigned d0[16];
            sfor<16>([&](auto I) { d0[I.v] = wsu[U_GFX + I.v * 512 + tid]; });
            {   // s[tt]: 8 threads per tt
                int tt = tid >> 3, pp = tid & 7;
                float acc = 0.f;
                #pragma unroll
                for (int c = 0; c < 4; ++c) {
                    float4 wx = *(const float4*)&big[tt * SWF + pp * 16 + c * 4];
                    float4 e4 = *(const float4*)&ebuf[pp * 16 + c * 4];
                    float4 v4 = *(const float4*)&vwf[pp * 16 + c * 4];
                    acc += ftanh(wx.x + e4.x) * v4.x + ftanh(wx.y + e4.y) * v4.y
                         + ftanh(wx.z + e4.z) * v4.z + ftanh(wx.w + e4.w) * v4.w;
                }
                acc += __shfl_xor(acc, 1, 8);
                acc += __shfl_xor(acc, 2, 8);
                acc += __shfl_xor(acc, 4, 8);
                if (pp == 0) sc[tt] = acc + V_b[0];
            }
            __syncthreads();
            if (tid < 64) {   // softmax(64) over time
                float v = sc[tid];
                float m = v;
                for (int d = 32; d; d >>= 1) m = fmaxf(m, __shfl_xor(m, d, 64));
                float e = __expf(v - m);
                float s = e;
                for (int d = 32; d; d >>= 1) s += __shfl_xor(s, d, 64);
                att[tid] = e / s;
            }
            __syncthreads();
            {   // din[k] = sum_t a[t]*final[t][k]; pack pairs 0..63
                int k = tid >> 2, pq = tid & 3;
                float acc = 0.f;
                #pragma unroll
                for (int u = 0; u < 16; ++u) {
                    int tt = u * 4 + pq;
                    acc += att[tt] * buf[tt][k];
                }
                acc += __shfl_xor(acc, 1, 64);
                acc += __shfl_xor(acc, 2, 64);
                float dp = __shfl_xor(acc, 4, 64);
                if ((tid & 7) == 0) xhp[tid >> 3] = pkh_d(acc, dp);
            }
            __syncthreads();
            {   // gates: streamed din chunks + resident h
                unsigned xA = xhp[lane], xB2 = xhp[64 + lane];
                float a = bgd;
                sfor<16>([&](auto I) { a = fdot2p(d0[I.v], __builtin_amdgcn_readlane(xA, I.v), a); });
                asm volatile("" ::: "memory");
                unsigned d1[16];
                sfor<16>([&](auto I) { d1[I.v] = wsu[U_GFX + (16 + I.v) * 512 + tid]; });
                sfor<16>([&](auto I) { a = fdot2p(d1[I.v], __builtin_amdgcn_readlane(xA, 16 + I.v), a); });
                asm volatile("" ::: "memory");
                unsigned d2[16];
                sfor<16>([&](auto I) { d2[I.v] = wsu[U_GFX + (32 + I.v) * 512 + tid]; });
                sfor<16>([&](auto I) { a = fdot2p(d2[I.v], __builtin_amdgcn_readlane(xA, 32 + I.v), a); });
                asm volatile("" ::: "memory");
                unsigned d3[16];
                sfor<16>([&](auto I) { d3[I.v] = wsu[U_GFX + (48 + I.v) * 512 + tid]; });
                sfor<16>([&](auto I) { a = fdot2p(d3[I.v], __builtin_amdgcn_readlane(xA, 48 + I.v), a); });
                sfor<64>([&](auto I) { a = fdot2p(wFh[I.v], __builtin_amdgcn_readlane(xB2, I.v), a); });
                pre[tid] = a;
            }
            __syncthreads();
            if (tid < 128) {   // pointwise + fused output partial
                int k = tid;
                float gi = pre[k], gf = pre[128 + k], gg = pre[256 + k], go = pre[384 + k];
                float c2 = fsig(gf) * creg + fsig(gi) * ftanh(gg);
                float h2v = fsig(go) * ftanh(c2);
                creg = c2;
                float hp = __shfl_xor(h2v, 1, 64);
                float cp = __shfl_xor(c2, 1, 64);
                if (!(k & 1)) {
                    unsigned hu = pkh_d(h2v, hp);
                    hcp[k >> 1] = hu;
                    hcp[64 + (k >> 1)] = pkh_d(c2, cp);
                    xhp[64 + (k >> 1)] = hu;
                }
                if (n >= 6) {
                    float v = h2v * rw[k];
                    for (int d = 32; d; d >>= 1) v += __shfl_xor(v, d, 64);
                    if (lane == 0) rsm[tid >> 6] = v;
                }
            }
            __syncthreads();
            if (n >= 6 && tid == 0)
                out[b * TDEC + (n - 6)] = rsm[0] + rsm[1] + reg_b[0];
        }
    }
}

extern "C" void kernel_launch(void* const* d_in, const int* in_sizes, int n_in,
                              void* d_out, int out_size, void* d_ws, size_t ws_size,
                              hipStream_t stream)
{
    const float* inq   = (const float*)d_in[0];
    const float* labp  = (const float*)d_in[1];
    const float* Wih1  = (const float*)d_in[2];
    const float* Whh1  = (const float*)d_in[3];
    const float* bih1  = (const float*)d_in[4];
    const float* bhh1  = (const float*)d_in[5];
    const float* Wih2  = (const float*)d_in[6];
    const float* Whh2  = (const float*)d_in[7];
    const float* bih2  = (const float*)d_in[8];
    const float* bhh2  = (const float*)d_in[9];
    const float* Wihd  = (const float*)d_in[10];
    const float* Whhd  = (const float*)d_in[11];
    const float* bihd  = (const float*)d_in[12];
    const float* bhhd  = (const float*)d_in[13];
    const float* Wi_w  = (const float*)d_in[14];
    const float* Wi_b  = (const float*)d_in[15];
    const float* We_w  = (const float*)d_in[16];
    const float* Vd_w  = (const float*)d_in[17];
    const float* Vd_b  = (const float*)d_in[18];
    const float* Wi2_w = (const float*)d_in[19];
    const float* Wi2_b = (const float*)d_in[20];
    const float* We2_w = (const float*)d_in[21];
    const float* Vd2_w = (const float*)d_in[22];
    const float* Vd2_b = (const float*)d_in[23];
    const float* Wx_w  = (const float*)d_in[24];
    const float* Wx_b  = (const float*)d_in[25];
    const float* Wh_w  = (const float*)d_in[26];
    const float* V_w   = (const float*)d_in[27];
    const float* V_b   = (const float*)d_in[28];
    const float* reg_w = (const float*)d_in[29];
    const float* reg_b = (const float*)d_in[30];
    float* ws  = (float*)d_ws;
    unsigned* wsu = (unsigned*)d_ws;
    float* out = (float*)d_out;

    pack_f3<<<dim3(16, 3), 256, 0, stream>>>(Wx_w, Wi_w, Wi2_w, ws);
    pack_gp<<<73, 512, 0, stream>>>(Wih1, Whh1, 17, 18, 0, U_GB, wsu);
    pack_gp<<<65, 512, 0, stream>>>(Wih2, Whh2, 129, 130, 0, U_GDX, wsu);
    pack_gp<<<64, 512, 0, stream>>>(Wih2, Whh2, 129, 130, 65, U_GDH, wsu);
    pack_gp<<<64, 512, 0, stream>>>(Wihd, Whhd, 128, 128, 0, U_GFX, wsu);
    pack_gp<<<64, 512, 0, stream>>>(Wihd, Whhd, 128, 128, 64, U_GFH, wsu);
    pack_ew<<<8, 1024, 0, stream>>>(We_w, 64, 8, 16, U_WE, wsu);
    pack_ew<<<8, 1024, 0, stream>>>(We2_w, 64, 8, 16, U_WE2, wsu);
    pack_ew<<<16, 1024, 0, stream>>>(Wh_w, 128, 4, 32, U_WH, wsu);
    dstp_main<<<512, 512, 0, stream>>>(inq, labp, bih1, bhh1, bih2, bhh2, bihd, bhhd,
                                       Wi_b, Vd_w, Vd_b, Wi2_b, Vd2_w, Vd2_b,
                                       Wx_b, V_w, V_b, reg_w, reg_b, ws, out);
}